// Round 2
// baseline (176.537 us; speedup 1.0000x reference)
//
#include <hip/hip_runtime.h>

#define NB 16384
#define XD 784
#define ZD 64
#define KK 64
#define LOG2PI_F 1.8378770664093453f
#define LDA 72   // padded row (shorts) for bf16 LDS tiles

typedef __attribute__((ext_vector_type(8))) short short8;
typedef __attribute__((ext_vector_type(4))) float floatx4;

// ws layout (bytes):
//   [0      .. 100352) : Wt[784][64] bf16
//   [100352 .. 108544) : Bi2[64][64] bf16   (0.5*exp(-2*plog))
//   [108544 .. 116736) : Bm1[64][64] bf16   (pmu * i2)
//   [116736 .. 116992) : Sk[64] f32
//   [116992 .. 117248) : Gk[64] f32
//   [117248 .. 117504) : Ck[64] f32
//   [117504 .. 121600) : dec_p[1024]
//   [121600 .. 125696) : kly_p[1024]
//   [125696 .. 129792) : klz_p[1024]
//   [129792 .. 129796) : arrival counter (u32), zeroed by prep each call
// Partials are written non-atomically (deterministic); only the arrival
// counter is atomic, so the final sum is bit-identical to the old
// finalize_kernel's double-precision tree.

__device__ __forceinline__ float wave_sum(float x) {
    #pragma unroll
    for (int o = 32; o > 0; o >>= 1) x += __shfl_xor(x, o, 64);
    return x;
}

__device__ __forceinline__ unsigned short f2bf(float f) {
    unsigned u = __float_as_uint(f);
    unsigned r = (u + 0x7FFF + ((u >> 16) & 1)) >> 16;  // RNE
    return (unsigned short)r;
}

__device__ __forceinline__ unsigned int pack2(float a, float b) {
    return (unsigned int)f2bf(a) | ((unsigned int)f2bf(b) << 16);
}

// Blocks 0..195: Wt transpose+cast. Block 196: per-component tables + counter=0.
__global__ __launch_bounds__(256) void prep_kernel(
    const float* __restrict__ W, const float* __restrict__ pmu_g,
    const float* __restrict__ plog_g,
    unsigned short* __restrict__ Wt, unsigned short* __restrict__ Bi2_g,
    unsigned short* __restrict__ Bm1_g, float* __restrict__ Sk_g,
    float* __restrict__ Gk_g, float* __restrict__ Ck_g,
    unsigned int* __restrict__ counter)
{
    const int tid = threadIdx.x;
    const int b = blockIdx.x;
    if (b < 196) {
        int idx = b * 256 + tid;   // 196*256 == 64*784 exactly
        int k = idx / XD;
        int n = idx - k * XD;
        Wt[n * ZD + k] = f2bf(W[idx]);
    } else {
        const int k = tid >> 2;
        const int q = tid & 3;
        const int v0 = q * 16;
        const int gb = k * 64 + v0;
        float s = 0.f, g = 0.f;
        unsigned int* pi2 = (unsigned int*)&Bi2_g[k * 64 + v0];
        unsigned int* pm1 = (unsigned int*)&Bm1_g[k * 64 + v0];
        #pragma unroll
        for (int i = 0; i < 4; ++i) {
            float4 mu4 = *(const float4*)&pmu_g[gb + 4 * i];
            float4 lg4 = *(const float4*)&plog_g[gb + 4 * i];
            float m0[4] = {mu4.x, mu4.y, mu4.z, mu4.w};
            float l0[4] = {lg4.x, lg4.y, lg4.z, lg4.w};
            float i2v[4], m1v[4];
            #pragma unroll
            for (int j = 0; j < 4; ++j) {
                float i2 = 0.5f * __expf(-2.f * l0[j]);
                i2v[j] = i2;
                m1v[j] = m0[j] * i2;
                g = fmaf(m0[j] * m0[j], i2, g);
                s += l0[j];
            }
            pi2[i * 2 + 0] = pack2(i2v[0], i2v[1]);
            pi2[i * 2 + 1] = pack2(i2v[2], i2v[3]);
            pm1[i * 2 + 0] = pack2(m1v[0], m1v[1]);
            pm1[i * 2 + 1] = pack2(m1v[2], m1v[3]);
        }
        s += __shfl_xor(s, 1, 64);
        s += __shfl_xor(s, 2, 64);
        g += __shfl_xor(g, 1, 64);
        g += __shfl_xor(g, 2, 64);
        if (q == 0) {
            Sk_g[k] = s;
            Gk_g[k] = g;
            Ck_g[k] = -s - 32.0f * LOG2PI_F;
        }
        if (tid == 0) *counter = 0u;
    }
}

// Fused mixture + decoder + last-block finalize: 16 rows/block, 1024 blocks.
__global__ __launch_bounds__(256) void fused_kernel(
    const float* __restrict__ x, const float* __restrict__ pi,
    const float* __restrict__ qmu, const float* __restrict__ qls,
    const float* __restrict__ eps,
    const unsigned short* __restrict__ Wt, const float* __restrict__ bd,
    const unsigned short* __restrict__ Bi2_g, const unsigned short* __restrict__ Bm1_g,
    const float* __restrict__ Sk_g, const float* __restrict__ Gk_g,
    const float* __restrict__ Ck_g,
    float* __restrict__ dec_p, float* __restrict__ kly_p, float* __restrict__ klz_p,
    unsigned int* __restrict__ counter, float* __restrict__ out)
{
    __shared__ unsigned short Az[16 * LDA];   // z
    __shared__ unsigned short Az2[16 * LDA];  // z^2
    __shared__ unsigned short Azm[16 * LDA];  // -2z
    __shared__ unsigned short Aq2[16 * LDA];  // qmu^2 + qs^2
    __shared__ unsigned short Aqm[16 * LDA];  // -2*qmu
    __shared__ float Lpi[16][68];             // log(pi) staged
    __shared__ float Sk_s[64], Gk_s[64], Ck_s[64], sql_s[16];
    __shared__ float MxP[4][16], SxP[4][16];
    __shared__ float r1[4], r2[4], rs[4];
    __shared__ unsigned int lastf;
    __shared__ double sred0[256], sred1[256], sred2[256];

    const int tid = threadIdx.x;
    const int row0 = blockIdx.x * 16;

    // ---- phase 1: z + mixture operands + log(pi) staging ----
    {
        const int r = tid >> 4;        // 0..15
        const int c = (tid & 15) * 4;  // 0..60
        const int gb = (row0 + r) * 64 + c;
        float4 mu4 = *(const float4*)&qmu[gb];
        float4 ls4 = *(const float4*)&qls[gb];
        float4 ep4 = *(const float4*)&eps[gb];
        float4 pi4 = *(const float4*)&pi[gb];   // same [B][64] layout as qmu
        float m0[4] = {mu4.x, mu4.y, mu4.z, mu4.w};
        float l0[4] = {ls4.x, ls4.y, ls4.z, ls4.w};
        float e0[4] = {ep4.x, ep4.y, ep4.z, ep4.w};
        float z[4], q2[4], sls = 0.f;
        #pragma unroll
        for (int j = 0; j < 4; ++j) {
            float qs = __expf(l0[j]);
            z[j] = fmaf(qs, e0[j], m0[j]);
            q2[j] = fmaf(m0[j], m0[j], qs * qs);
            sls += l0[j];
        }
        unsigned* pa = (unsigned*)&Az[r * LDA + c];
        pa[0] = pack2(z[0], z[1]);               pa[1] = pack2(z[2], z[3]);
        unsigned* pb = (unsigned*)&Az2[r * LDA + c];
        pb[0] = pack2(z[0] * z[0], z[1] * z[1]); pb[1] = pack2(z[2] * z[2], z[3] * z[3]);
        unsigned* pc = (unsigned*)&Azm[r * LDA + c];
        pc[0] = pack2(-2.f * z[0], -2.f * z[1]); pc[1] = pack2(-2.f * z[2], -2.f * z[3]);
        unsigned* pd = (unsigned*)&Aq2[r * LDA + c];
        pd[0] = pack2(q2[0], q2[1]);             pd[1] = pack2(q2[2], q2[3]);
        unsigned* pe = (unsigned*)&Aqm[r * LDA + c];
        pe[0] = pack2(-2.f * m0[0], -2.f * m0[1]); pe[1] = pack2(-2.f * m0[2], -2.f * m0[3]);
        float4 lp4;
        lp4.x = __logf(pi4.x); lp4.y = __logf(pi4.y);
        lp4.z = __logf(pi4.z); lp4.w = __logf(pi4.w);
        *(float4*)&Lpi[r][c] = lp4;
        sls += __shfl_xor(sls, 1, 64);
        sls += __shfl_xor(sls, 2, 64);
        sls += __shfl_xor(sls, 4, 64);
        sls += __shfl_xor(sls, 8, 64);
        if ((tid & 15) == 0) sql_s[r] = sls;
        if (tid < 64) {
            Sk_s[tid] = Sk_g[tid];
            Gk_s[tid] = Gk_g[tid];
            Ck_s[tid] = Ck_g[tid];
        }
    }

    const int lane = tid & 63;
    const int w    = tid >> 6;
    const int m    = lane & 15;
    const int quad = lane >> 4;
    const int kk   = w * 16 + m;

    // ---- early issue of decoder tile-0 x/bd loads (land during MFMA+epilogue) ----
    const int xrow = (row0 + quad * 4) * XD;
    float xa0, xa1, xa2, xa3, bb;
    {
        const int col = w * 16 + m;
        xa0 = x[xrow + 0 * XD + col];
        xa1 = x[xrow + 1 * XD + col];
        xa2 = x[xrow + 2 * XD + col];
        xa3 = x[xrow + 3 * XD + col];
        bb  = bd[col];
    }
    __syncthreads();

    // ---- mixture MFMA: k-tile w (A-frags loaded in pairs to cap VGPR) ----
    floatx4 ca = {0.f, 0.f, 0.f, 0.f}, cc = {0.f, 0.f, 0.f, 0.f};
    {
        const short8 bi0 = *(const short8*)&Bi2_g[kk * 64 + quad * 8];
        const short8 bi1 = *(const short8*)&Bi2_g[kk * 64 + 32 + quad * 8];
        const short8 bm0 = *(const short8*)&Bm1_g[kk * 64 + quad * 8];
        const short8 bm1 = *(const short8*)&Bm1_g[kk * 64 + 32 + quad * 8];
        {
            const short8 a0 = *(const short8*)&Az2[m * LDA + quad * 8];
            const short8 a1 = *(const short8*)&Az2[m * LDA + 32 + quad * 8];
            ca = __builtin_amdgcn_mfma_f32_16x16x32_bf16(a0, bi0, ca, 0, 0, 0);
            ca = __builtin_amdgcn_mfma_f32_16x16x32_bf16(a1, bi1, ca, 0, 0, 0);
        }
        {
            const short8 a0 = *(const short8*)&Aq2[m * LDA + quad * 8];
            const short8 a1 = *(const short8*)&Aq2[m * LDA + 32 + quad * 8];
            cc = __builtin_amdgcn_mfma_f32_16x16x32_bf16(a0, bi0, cc, 0, 0, 0);
            cc = __builtin_amdgcn_mfma_f32_16x16x32_bf16(a1, bi1, cc, 0, 0, 0);
        }
        {
            const short8 a0 = *(const short8*)&Azm[m * LDA + quad * 8];
            const short8 a1 = *(const short8*)&Azm[m * LDA + 32 + quad * 8];
            ca = __builtin_amdgcn_mfma_f32_16x16x32_bf16(a0, bm0, ca, 0, 0, 0);
            ca = __builtin_amdgcn_mfma_f32_16x16x32_bf16(a1, bm1, ca, 0, 0, 0);
        }
        {
            const short8 a0 = *(const short8*)&Aqm[m * LDA + quad * 8];
            const short8 a1 = *(const short8*)&Aqm[m * LDA + 32 + quad * 8];
            cc = __builtin_amdgcn_mfma_f32_16x16x32_bf16(a0, bm0, cc, 0, 0, 0);
            cc = __builtin_amdgcn_mfma_f32_16x16x32_bf16(a1, bm1, cc, 0, 0, 0);
        }
    }

    // ---- epilogue part 1: per-wave row stats over this wave's 16 k ----
    const float ckv = Ck_s[kk], gkv = Gk_s[kk], skv = Sk_s[kk];
    float comp[4], ev[4], mxw[4], sw[4];
    #pragma unroll
    for (int r = 0; r < 4; ++r) {
        comp[r] = ckv - (ca[r] + gkv);
        float pzv = comp[r] + Lpi[quad * 4 + r][kk];
        float mx = pzv;
        #pragma unroll
        for (int o = 1; o <= 8; o <<= 1) mx = fmaxf(mx, __shfl_xor(mx, o, 64));
        float e = __expf(pzv - mx);
        float s = e;
        #pragma unroll
        for (int o = 1; o <= 8; o <<= 1) s += __shfl_xor(s, o, 64);
        mxw[r] = mx; sw[r] = s; ev[r] = e;
    }
    if (m == 0) {
        #pragma unroll
        for (int r = 0; r < 4; ++r) {
            MxP[w][quad * 4 + r] = mxw[r];
            SxP[w][quad * 4 + r] = sw[r];
        }
    }
    __syncthreads();

    // ---- epilogue part 2: cross-wave LSE merge + KL accumulation ----
    float kly = 0.f, klz = 0.f;
    #pragma unroll
    for (int r = 0; r < 4; ++r) {
        const int row = quad * 4 + r;
        float g0 = MxP[0][row], g1 = MxP[1][row], g2 = MxP[2][row], g3 = MxP[3][row];
        float gmx = fmaxf(fmaxf(g0, g1), fmaxf(g2, g3));
        float st = SxP[0][row] * __expf(g0 - gmx) + SxP[1][row] * __expf(g1 - gmx)
                 + SxP[2][row] * __expf(g2 - gmx) + SxP[3][row] * __expf(g3 - gmx);
        float lse = gmx + __logf(st);
        float p = ev[r] * __expf(mxw[r] - gmx) * __frcp_rn(st);
        kly = fmaf(p, comp[r] - lse, kly);
        klz = fmaf(p, skv - sql_s[row] + cc[r] + gkv - 32.0f, klz);
    }
    kly = wave_sum(kly);
    klz = wave_sum(klz);
    if (lane == 0) { r1[w] = kly; r2[w] = klz; }

    // ---- decoder phase: software-pipelined col-tile loop ----
    const short8 af0 = *(const short8*)&Az[m * LDA + quad * 8];
    const short8 af1 = *(const short8*)&Az[m * LDA + 32 + quad * 8];
    short8 w0, w1;
    {
        const int col = w * 16 + m;
        w0 = *(const short8*)&Wt[col * 64 + quad * 8];
        w1 = *(const short8*)&Wt[col * 64 + 32 + quad * 8];
    }

    float accl = 0.f;
    #pragma unroll 1
    for (int t = w; t < 49; t += 4) {
        const float cx0 = xa0, cx1 = xa1, cx2 = xa2, cx3 = xa3, cb = bb;
        const short8 cw0 = w0, cw1 = w1;
        const int tn = t + 4;
        if (tn < 49) {
            const int col = tn * 16 + m;
            xa0 = x[xrow + 0 * XD + col];
            xa1 = x[xrow + 1 * XD + col];
            xa2 = x[xrow + 2 * XD + col];
            xa3 = x[xrow + 3 * XD + col];
            bb  = bd[col];
            w0  = *(const short8*)&Wt[col * 64 + quad * 8];
            w1  = *(const short8*)&Wt[col * 64 + 32 + quad * 8];
        }
        floatx4 c = {0.f, 0.f, 0.f, 0.f};
        c = __builtin_amdgcn_mfma_f32_16x16x32_bf16(af0, cw0, c, 0, 0, 0);
        c = __builtin_amdgcn_mfma_f32_16x16x32_bf16(af1, cw1, c, 0, 0, 0);
        float d0 = cx0 - (c[0] + cb);
        float d1 = cx1 - (c[1] + cb);
        float d2 = cx2 - (c[2] + cb);
        float d3 = cx3 - (c[3] + cb);
        accl = fmaf(d0, d0, accl);
        accl = fmaf(d1, d1, accl);
        accl = fmaf(d2, d2, accl);
        accl = fmaf(d3, d3, accl);
    }

    float sdec = wave_sum(accl);
    if (lane == 0) rs[w] = sdec;
    __syncthreads();

    // ---- partial store + arrival counter; last block finalizes ----
    if (tid == 0) {
        dec_p[blockIdx.x] = -0.5f * (rs[0] + rs[1] + rs[2] + rs[3]);
        kly_p[blockIdx.x] = r1[0] + r1[1] + r1[2] + r1[3];
        klz_p[blockIdx.x] = r2[0] + r2[1] + r2[2] + r2[3];
        __threadfence();
        unsigned int t = __hip_atomic_fetch_add(counter, 1u, __ATOMIC_ACQ_REL,
                                                __HIP_MEMORY_SCOPE_AGENT);
        lastf = (t == (unsigned int)(gridDim.x - 1)) ? 1u : 0u;
    }
    __syncthreads();
    if (lastf) {
        __threadfence();  // acquire side: invalidate local caches before reading partials
        const volatile float* dp = (const volatile float*)dec_p;
        const volatile float* yp = (const volatile float*)kly_p;
        const volatile float* zp = (const volatile float*)klz_p;
        double a0 = 0.0, a1 = 0.0, a2 = 0.0;
        for (int i = tid; i < 1024; i += 256) {
            a0 += (double)dp[i];
            a1 += (double)yp[i];
            a2 += (double)zp[i];
        }
        sred0[tid] = a0; sred1[tid] = a1; sred2[tid] = a2;
        __syncthreads();
        #pragma unroll
        for (int off = 128; off > 0; off >>= 1) {
            if (tid < off) {
                sred0[tid] += sred0[tid + off];
                sred1[tid] += sred1[tid + off];
                sred2[tid] += sred2[tid + off];
            }
            __syncthreads();
        }
        if (tid == 0) {
            double lpx = sred0[0] - 0.5 * 1.8378770664093453 * (double)NB * (double)XD;
            out[0] = (float)((lpx - sred1[0] - sred2[0]) / (double)NB);
        }
    }
}

extern "C" void kernel_launch(void* const* d_in, const int* in_sizes, int n_in,
                              void* d_out, int out_size, void* d_ws, size_t ws_size,
                              hipStream_t stream) {
    const float* x    = (const float*)d_in[0];
    const float* pi   = (const float*)d_in[1];
    const float* qmu  = (const float*)d_in[2];
    const float* qls  = (const float*)d_in[3];
    const float* eps  = (const float*)d_in[4];
    const float* pmu  = (const float*)d_in[5];
    const float* plog = (const float*)d_in[6];
    const float* W    = (const float*)d_in[7];
    const float* bd   = (const float*)d_in[8];
    float* out = (float*)d_out;

    char* wsb = (char*)d_ws;
    unsigned short* Wt   = (unsigned short*)(wsb);
    unsigned short* Bi2g = (unsigned short*)(wsb + 100352);
    unsigned short* Bm1g = (unsigned short*)(wsb + 108544);
    float* Skg   = (float*)(wsb + 116736);
    float* Gkg   = (float*)(wsb + 116992);
    float* Ckg   = (float*)(wsb + 117248);
    float* dec_p = (float*)(wsb + 117504);
    float* kly_p = (float*)(wsb + 121600);
    float* klz_p = (float*)(wsb + 125696);
    unsigned int* counter = (unsigned int*)(wsb + 129792);

    prep_kernel<<<197, 256, 0, stream>>>(W, pmu, plog, Wt, Bi2g, Bm1g, Skg, Gkg, Ckg, counter);
    fused_kernel<<<NB / 16, 256, 0, stream>>>(x, pi, qmu, qls, eps, Wt, bd,
                                              Bi2g, Bm1g, Skg, Gkg, Ckg,
                                              dec_p, kly_p, klz_p, counter, out);
}

// Round 3
// 124.528 us; speedup vs baseline: 1.4177x; 1.4177x over previous
//
#include <hip/hip_runtime.h>

#define NB 16384
#define XD 784
#define ZD 64
#define KK 64
#define LOG2PI_F 1.8378770664093453f
#define LDA 72   // padded row (shorts) for bf16 LDS tiles

typedef __attribute__((ext_vector_type(8))) short short8;
typedef __attribute__((ext_vector_type(4))) float floatx4;

// ws layout (bytes):
//   [0      .. 100352) : Wt[784][64] bf16
//   [100352 .. 108544) : Bi2[64][64] bf16   (0.5*exp(-2*plog))
//   [108544 .. 116736) : Bm1[64][64] bf16   (pmu * i2)
//   [116736 .. 116992) : Sk[64] f32
//   [116992 .. 117248) : Gk[64] f32
//   [117248 .. 117504) : Ck[64] f32
//   [117504 .. 121600) : dec_p[1024]
//   [121600 .. 125696) : kly_p[1024]
//   [125696 .. 129792) : klz_p[1024]
// No atomics/fences anywhere: every slot written unconditionally each call;
// finalize runs as a separate dispatch (kernel boundary = coherence point).

__device__ __forceinline__ float wave_sum(float x) {
    #pragma unroll
    for (int o = 32; o > 0; o >>= 1) x += __shfl_xor(x, o, 64);
    return x;
}

__device__ __forceinline__ unsigned short f2bf(float f) {
    unsigned u = __float_as_uint(f);
    unsigned r = (u + 0x7FFF + ((u >> 16) & 1)) >> 16;  // RNE
    return (unsigned short)r;
}

__device__ __forceinline__ unsigned int pack2(float a, float b) {
    return (unsigned int)f2bf(a) | ((unsigned int)f2bf(b) << 16);
}

// Blocks 0..195: Wt transpose+cast. Block 196: per-component tables.
__global__ __launch_bounds__(256) void prep_kernel(
    const float* __restrict__ W, const float* __restrict__ pmu_g,
    const float* __restrict__ plog_g,
    unsigned short* __restrict__ Wt, unsigned short* __restrict__ Bi2_g,
    unsigned short* __restrict__ Bm1_g, float* __restrict__ Sk_g,
    float* __restrict__ Gk_g, float* __restrict__ Ck_g)
{
    const int tid = threadIdx.x;
    const int b = blockIdx.x;
    if (b < 196) {
        int idx = b * 256 + tid;   // 196*256 == 64*784 exactly
        int k = idx / XD;
        int n = idx - k * XD;
        Wt[n * ZD + k] = f2bf(W[idx]);
    } else {
        const int k = tid >> 2;
        const int q = tid & 3;
        const int v0 = q * 16;
        const int gb = k * 64 + v0;
        float s = 0.f, g = 0.f;
        unsigned int* pi2 = (unsigned int*)&Bi2_g[k * 64 + v0];
        unsigned int* pm1 = (unsigned int*)&Bm1_g[k * 64 + v0];
        #pragma unroll
        for (int i = 0; i < 4; ++i) {
            float4 mu4 = *(const float4*)&pmu_g[gb + 4 * i];
            float4 lg4 = *(const float4*)&plog_g[gb + 4 * i];
            float m0[4] = {mu4.x, mu4.y, mu4.z, mu4.w};
            float l0[4] = {lg4.x, lg4.y, lg4.z, lg4.w};
            float i2v[4], m1v[4];
            #pragma unroll
            for (int j = 0; j < 4; ++j) {
                float i2 = 0.5f * __expf(-2.f * l0[j]);
                i2v[j] = i2;
                m1v[j] = m0[j] * i2;
                g = fmaf(m0[j] * m0[j], i2, g);
                s += l0[j];
            }
            pi2[i * 2 + 0] = pack2(i2v[0], i2v[1]);
            pi2[i * 2 + 1] = pack2(i2v[2], i2v[3]);
            pm1[i * 2 + 0] = pack2(m1v[0], m1v[1]);
            pm1[i * 2 + 1] = pack2(m1v[2], m1v[3]);
        }
        s += __shfl_xor(s, 1, 64);
        s += __shfl_xor(s, 2, 64);
        g += __shfl_xor(g, 1, 64);
        g += __shfl_xor(g, 2, 64);
        if (q == 0) {
            Sk_g[k] = s;
            Gk_g[k] = g;
            Ck_g[k] = -s - 32.0f * LOG2PI_F;
        }
    }
}

// Fused mixture + decoder: 16 rows/block, 1024 blocks, 4 waves.
__global__ __launch_bounds__(256) void fused_kernel(
    const float* __restrict__ x, const float* __restrict__ pi,
    const float* __restrict__ qmu, const float* __restrict__ qls,
    const float* __restrict__ eps,
    const unsigned short* __restrict__ Wt, const float* __restrict__ bd,
    const unsigned short* __restrict__ Bi2_g, const unsigned short* __restrict__ Bm1_g,
    const float* __restrict__ Sk_g, const float* __restrict__ Gk_g,
    const float* __restrict__ Ck_g,
    float* __restrict__ dec_p, float* __restrict__ kly_p, float* __restrict__ klz_p)
{
    __shared__ unsigned short Az[16 * LDA];   // z
    __shared__ unsigned short Az2[16 * LDA];  // z^2
    __shared__ unsigned short Azm[16 * LDA];  // -2z
    __shared__ unsigned short Aq2[16 * LDA];  // qmu^2 + qs^2
    __shared__ unsigned short Aqm[16 * LDA];  // -2*qmu
    __shared__ float Lpi[16][68];             // log(pi) staged (coalesced in)
    __shared__ float Sk_s[64], Gk_s[64], Ck_s[64], sql_s[16];
    __shared__ float MxP[4][16], SxP[4][16];
    __shared__ float r1[4], r2[4], rs[4];

    const int tid = threadIdx.x;
    const int row0 = blockIdx.x * 16;

    // ---- phase 1: z + mixture operands + log(pi) staging ----
    {
        const int r = tid >> 4;        // 0..15
        const int c = (tid & 15) * 4;  // 0..60
        const int gb = (row0 + r) * 64 + c;
        float4 mu4 = *(const float4*)&qmu[gb];
        float4 ls4 = *(const float4*)&qls[gb];
        float4 ep4 = *(const float4*)&eps[gb];
        float4 pi4 = *(const float4*)&pi[gb];   // same [B][64] layout as qmu
        float m0[4] = {mu4.x, mu4.y, mu4.z, mu4.w};
        float l0[4] = {ls4.x, ls4.y, ls4.z, ls4.w};
        float e0[4] = {ep4.x, ep4.y, ep4.z, ep4.w};
        float z[4], q2[4], sls = 0.f;
        #pragma unroll
        for (int j = 0; j < 4; ++j) {
            float qs = __expf(l0[j]);
            z[j] = fmaf(qs, e0[j], m0[j]);
            q2[j] = fmaf(m0[j], m0[j], qs * qs);
            sls += l0[j];
        }
        unsigned* pa = (unsigned*)&Az[r * LDA + c];
        pa[0] = pack2(z[0], z[1]);               pa[1] = pack2(z[2], z[3]);
        unsigned* pb = (unsigned*)&Az2[r * LDA + c];
        pb[0] = pack2(z[0] * z[0], z[1] * z[1]); pb[1] = pack2(z[2] * z[2], z[3] * z[3]);
        unsigned* pc = (unsigned*)&Azm[r * LDA + c];
        pc[0] = pack2(-2.f * z[0], -2.f * z[1]); pc[1] = pack2(-2.f * z[2], -2.f * z[3]);
        unsigned* pd = (unsigned*)&Aq2[r * LDA + c];
        pd[0] = pack2(q2[0], q2[1]);             pd[1] = pack2(q2[2], q2[3]);
        unsigned* pe = (unsigned*)&Aqm[r * LDA + c];
        pe[0] = pack2(-2.f * m0[0], -2.f * m0[1]); pe[1] = pack2(-2.f * m0[2], -2.f * m0[3]);
        float4 lp4;
        lp4.x = __logf(pi4.x); lp4.y = __logf(pi4.y);
        lp4.z = __logf(pi4.z); lp4.w = __logf(pi4.w);
        *(float4*)&Lpi[r][c] = lp4;
        sls += __shfl_xor(sls, 1, 64);
        sls += __shfl_xor(sls, 2, 64);
        sls += __shfl_xor(sls, 4, 64);
        sls += __shfl_xor(sls, 8, 64);
        if ((tid & 15) == 0) sql_s[r] = sls;
        if (tid < 64) {
            Sk_s[tid] = Sk_g[tid];
            Gk_s[tid] = Gk_g[tid];
            Ck_s[tid] = Ck_g[tid];
        }
    }

    const int lane = tid & 63;
    const int w    = tid >> 6;
    const int m    = lane & 15;
    const int quad = lane >> 4;
    const int kk   = w * 16 + m;

    // ---- early issue of decoder tile-0 x/bd loads (land during MFMA+epilogue) ----
    const int xrow = (row0 + quad * 4) * XD;
    float xa0, xa1, xa2, xa3, bb;
    {
        const int col = w * 16 + m;
        xa0 = x[xrow + 0 * XD + col];
        xa1 = x[xrow + 1 * XD + col];
        xa2 = x[xrow + 2 * XD + col];
        xa3 = x[xrow + 3 * XD + col];
        bb  = bd[col];
    }
    __syncthreads();

    // ---- mixture MFMA: k-tile w (A-frags loaded in pairs to cap VGPR) ----
    floatx4 ca = {0.f, 0.f, 0.f, 0.f}, cc = {0.f, 0.f, 0.f, 0.f};
    {
        const short8 bi0 = *(const short8*)&Bi2_g[kk * 64 + quad * 8];
        const short8 bi1 = *(const short8*)&Bi2_g[kk * 64 + 32 + quad * 8];
        const short8 bm0 = *(const short8*)&Bm1_g[kk * 64 + quad * 8];
        const short8 bm1 = *(const short8*)&Bm1_g[kk * 64 + 32 + quad * 8];
        {
            const short8 a0 = *(const short8*)&Az2[m * LDA + quad * 8];
            const short8 a1 = *(const short8*)&Az2[m * LDA + 32 + quad * 8];
            ca = __builtin_amdgcn_mfma_f32_16x16x32_bf16(a0, bi0, ca, 0, 0, 0);
            ca = __builtin_amdgcn_mfma_f32_16x16x32_bf16(a1, bi1, ca, 0, 0, 0);
        }
        {
            const short8 a0 = *(const short8*)&Aq2[m * LDA + quad * 8];
            const short8 a1 = *(const short8*)&Aq2[m * LDA + 32 + quad * 8];
            cc = __builtin_amdgcn_mfma_f32_16x16x32_bf16(a0, bi0, cc, 0, 0, 0);
            cc = __builtin_amdgcn_mfma_f32_16x16x32_bf16(a1, bi1, cc, 0, 0, 0);
        }
        {
            const short8 a0 = *(const short8*)&Azm[m * LDA + quad * 8];
            const short8 a1 = *(const short8*)&Azm[m * LDA + 32 + quad * 8];
            ca = __builtin_amdgcn_mfma_f32_16x16x32_bf16(a0, bm0, ca, 0, 0, 0);
            ca = __builtin_amdgcn_mfma_f32_16x16x32_bf16(a1, bm1, ca, 0, 0, 0);
        }
        {
            const short8 a0 = *(const short8*)&Aqm[m * LDA + quad * 8];
            const short8 a1 = *(const short8*)&Aqm[m * LDA + 32 + quad * 8];
            cc = __builtin_amdgcn_mfma_f32_16x16x32_bf16(a0, bm0, cc, 0, 0, 0);
            cc = __builtin_amdgcn_mfma_f32_16x16x32_bf16(a1, bm1, cc, 0, 0, 0);
        }
    }

    // ---- epilogue part 1: per-wave row stats over this wave's 16 k ----
    const float ckv = Ck_s[kk], gkv = Gk_s[kk], skv = Sk_s[kk];
    float comp[4], ev[4], mxw[4], sw[4];
    #pragma unroll
    for (int r = 0; r < 4; ++r) {
        comp[r] = ckv - (ca[r] + gkv);
        float pzv = comp[r] + Lpi[quad * 4 + r][kk];
        float mx = pzv;
        #pragma unroll
        for (int o = 1; o <= 8; o <<= 1) mx = fmaxf(mx, __shfl_xor(mx, o, 64));
        float e = __expf(pzv - mx);
        float s = e;
        #pragma unroll
        for (int o = 1; o <= 8; o <<= 1) s += __shfl_xor(s, o, 64);
        mxw[r] = mx; sw[r] = s; ev[r] = e;
    }
    if (m == 0) {
        #pragma unroll
        for (int r = 0; r < 4; ++r) {
            MxP[w][quad * 4 + r] = mxw[r];
            SxP[w][quad * 4 + r] = sw[r];
        }
    }
    __syncthreads();

    // ---- epilogue part 2: cross-wave LSE merge + KL accumulation ----
    float kly = 0.f, klz = 0.f;
    #pragma unroll
    for (int r = 0; r < 4; ++r) {
        const int row = quad * 4 + r;
        float g0 = MxP[0][row], g1 = MxP[1][row], g2 = MxP[2][row], g3 = MxP[3][row];
        float gmx = fmaxf(fmaxf(g0, g1), fmaxf(g2, g3));
        float st = SxP[0][row] * __expf(g0 - gmx) + SxP[1][row] * __expf(g1 - gmx)
                 + SxP[2][row] * __expf(g2 - gmx) + SxP[3][row] * __expf(g3 - gmx);
        float lse = gmx + __logf(st);
        float p = ev[r] * __expf(mxw[r] - gmx) * __frcp_rn(st);
        kly = fmaf(p, comp[r] - lse, kly);
        klz = fmaf(p, skv - sql_s[row] + cc[r] + gkv - 32.0f, klz);
    }
    kly = wave_sum(kly);
    klz = wave_sum(klz);
    if (lane == 0) { r1[w] = kly; r2[w] = klz; }

    // ---- decoder phase: software-pipelined col-tile loop ----
    const short8 af0 = *(const short8*)&Az[m * LDA + quad * 8];
    const short8 af1 = *(const short8*)&Az[m * LDA + 32 + quad * 8];
    short8 w0, w1;
    {
        const int col = w * 16 + m;
        w0 = *(const short8*)&Wt[col * 64 + quad * 8];
        w1 = *(const short8*)&Wt[col * 64 + 32 + quad * 8];
    }

    float accl = 0.f;
    #pragma unroll 1
    for (int t = w; t < 49; t += 4) {
        const float cx0 = xa0, cx1 = xa1, cx2 = xa2, cx3 = xa3, cb = bb;
        const short8 cw0 = w0, cw1 = w1;
        const int tn = t + 4;
        if (tn < 49) {
            const int col = tn * 16 + m;
            xa0 = x[xrow + 0 * XD + col];
            xa1 = x[xrow + 1 * XD + col];
            xa2 = x[xrow + 2 * XD + col];
            xa3 = x[xrow + 3 * XD + col];
            bb  = bd[col];
            w0  = *(const short8*)&Wt[col * 64 + quad * 8];
            w1  = *(const short8*)&Wt[col * 64 + 32 + quad * 8];
        }
        floatx4 c = {0.f, 0.f, 0.f, 0.f};
        c = __builtin_amdgcn_mfma_f32_16x16x32_bf16(af0, cw0, c, 0, 0, 0);
        c = __builtin_amdgcn_mfma_f32_16x16x32_bf16(af1, cw1, c, 0, 0, 0);
        float d0 = cx0 - (c[0] + cb);
        float d1 = cx1 - (c[1] + cb);
        float d2 = cx2 - (c[2] + cb);
        float d3 = cx3 - (c[3] + cb);
        accl = fmaf(d0, d0, accl);
        accl = fmaf(d1, d1, accl);
        accl = fmaf(d2, d2, accl);
        accl = fmaf(d3, d3, accl);
    }

    float sdec = wave_sum(accl);
    if (lane == 0) rs[w] = sdec;
    __syncthreads();
    if (tid == 0) {
        dec_p[blockIdx.x] = -0.5f * (rs[0] + rs[1] + rs[2] + rs[3]);
        kly_p[blockIdx.x] = r1[0] + r1[1] + r1[2] + r1[3];
        klz_p[blockIdx.x] = r2[0] + r2[1] + r2[2] + r2[3];
    }
}

// Single-block reduction of all partials -> elbo.
__global__ __launch_bounds__(256) void finalize_kernel(
    const float* __restrict__ dec_p, const float* __restrict__ kly_p,
    const float* __restrict__ klz_p, float* __restrict__ out)
{
    __shared__ double s0[256], s1[256], s2[256];
    const int tid = threadIdx.x;
    double a0 = 0.0, a1 = 0.0, a2 = 0.0;
    for (int i = tid; i < 1024; i += 256) {
        a0 += (double)dec_p[i];
        a1 += (double)kly_p[i];
        a2 += (double)klz_p[i];
    }
    s0[tid] = a0; s1[tid] = a1; s2[tid] = a2;
    __syncthreads();
    #pragma unroll
    for (int off = 128; off > 0; off >>= 1) {
        if (tid < off) {
            s0[tid] += s0[tid + off];
            s1[tid] += s1[tid + off];
            s2[tid] += s2[tid + off];
        }
        __syncthreads();
    }
    if (tid == 0) {
        double lpx = s0[0] - 0.5 * 1.8378770664093453 * (double)NB * (double)XD;
        out[0] = (float)((lpx - s1[0] - s2[0]) / (double)NB);
    }
}

extern "C" void kernel_launch(void* const* d_in, const int* in_sizes, int n_in,
                              void* d_out, int out_size, void* d_ws, size_t ws_size,
                              hipStream_t stream) {
    const float* x    = (const float*)d_in[0];
    const float* pi   = (const float*)d_in[1];
    const float* qmu  = (const float*)d_in[2];
    const float* qls  = (const float*)d_in[3];
    const float* eps  = (const float*)d_in[4];
    const float* pmu  = (const float*)d_in[5];
    const float* plog = (const float*)d_in[6];
    const float* W    = (const float*)d_in[7];
    const float* bd   = (const float*)d_in[8];
    float* out = (float*)d_out;

    char* wsb = (char*)d_ws;
    unsigned short* Wt   = (unsigned short*)(wsb);
    unsigned short* Bi2g = (unsigned short*)(wsb + 100352);
    unsigned short* Bm1g = (unsigned short*)(wsb + 108544);
    float* Skg   = (float*)(wsb + 116736);
    float* Gkg   = (float*)(wsb + 116992);
    float* Ckg   = (float*)(wsb + 117248);
    float* dec_p = (float*)(wsb + 117504);
    float* kly_p = (float*)(wsb + 121600);
    float* klz_p = (float*)(wsb + 125696);

    prep_kernel<<<197, 256, 0, stream>>>(W, pmu, plog, Wt, Bi2g, Bm1g, Skg, Gkg, Ckg);
    fused_kernel<<<NB / 16, 256, 0, stream>>>(x, pi, qmu, qls, eps, Wt, bd,
                                              Bi2g, Bm1g, Skg, Gkg, Ckg,
                                              dec_p, kly_p, klz_p);
    finalize_kernel<<<1, 256, 0, stream>>>(dec_p, kly_p, klz_p, out);
}